// Round 6
// baseline (219.698 us; speedup 1.0000x reference)
//
#include <hip/hip_runtime.h>

#define NN 50000
#define NC 64
#define NE 800000
#define NQUAD (NN / 4)          // 12500 4-node work items
#define GBLK 1042               // 4168 waves -> 3 quads/wave (near-perfect)
#define NWAVES (GBLK * 4)
#define CONV_BLK 3125           // NN*NC/4 float4s / 256 threads
#define CNT_BLK  782            // ceil(NE/4 / 256)
#define OFF_BLK  196            // ceil(NN / 256)

__device__ __forceinline__ unsigned short f32_to_bf16_rne(float v) {
    unsigned u = __float_as_uint(v);
    u = (u + 0x7fffu + ((u >> 16) & 1u)) >> 16;
    return (unsigned short)u;
}

// ---------------------------------------------------------------------------
// Kernel 1: fused x->bf16 convert (blocks [0,CONV_BLK)) + in-degree count.
// ---------------------------------------------------------------------------
__global__ __launch_bounds__(256) void convert_count_kernel(
        const float4* __restrict__ x4, ushort4* __restrict__ xh4,
        const int4* __restrict__ col4, int* __restrict__ cnt, int do_conv) {
    int b = blockIdx.x;
    if (do_conv && b < CONV_BLK) {
        int i = b * 256 + threadIdx.x;          // < NN*NC/4 exactly
        float4 v = x4[i];
        ushort4 h;
        h.x = f32_to_bf16_rne(v.x); h.y = f32_to_bf16_rne(v.y);
        h.z = f32_to_bf16_rne(v.z); h.w = f32_to_bf16_rne(v.w);
        xh4[i] = h;
        return;
    }
    int cb = do_conv ? b - CONV_BLK : b;
    int t = cb * 256 + threadIdx.x;
    if (t < NE / 4) {
        int4 c = col4[t];
        atomicAdd(&cnt[c.x], 1); atomicAdd(&cnt[c.y], 1);
        atomicAdd(&cnt[c.z], 1); atomicAdd(&cnt[c.w], 1);
    }
}

// ---------------------------------------------------------------------------
// Kernel 2: offsets — block-local exclusive scan + atomic block base.
// off[] is a valid (non-monotone) partition; lengths come from cnt[].
// ---------------------------------------------------------------------------
__global__ __launch_bounds__(256) void offsets_kernel(
        const int* __restrict__ cnt, int* __restrict__ off,
        int* __restrict__ gctr) {
    __shared__ int s[256];
    __shared__ int base;
    int t = threadIdx.x;
    int i = blockIdx.x * 256 + t;
    int v = (i < NN) ? cnt[i] : 0;
    s[t] = v;
    __syncthreads();
#pragma unroll
    for (int d = 1; d < 256; d <<= 1) {
        int u = (t >= d) ? s[t - d] : 0;
        __syncthreads();
        s[t] += u;
        __syncthreads();
    }
    int excl = s[t] - v;
    if (t == 255) base = atomicAdd(gctr, s[255]);
    __syncthreads();
    if (i < NN) off[i] = base + excl;
}

// ---------------------------------------------------------------------------
// Kernel 3: CSR fill — 4 edges/thread, int atomic cursors
// ---------------------------------------------------------------------------
__global__ __launch_bounds__(256) void fill_kernel(
        const int4* __restrict__ row4, const int4* __restrict__ col4,
        const int* __restrict__ off, int* __restrict__ cursor,
        int* __restrict__ perm) {
    int t = blockIdx.x * blockDim.x + threadIdx.x;
    if (t < NE / 4) {
        int4 r = row4[t];
        int4 c = col4[t];
        perm[off[c.x] + atomicAdd(&cursor[c.x], 1)] = r.x;
        perm[off[c.y] + atomicAdd(&cursor[c.y], 1)] = r.y;
        perm[off[c.z] + atomicAdd(&cursor[c.z], 1)] = r.z;
        perm[off[c.w] + atomicAdd(&cursor[c.w], 1)] = r.w;
    }
}

// ---------------------------------------------------------------------------
// Kernel 4: fused gather + mean + concat + linear.
// BF16=true: neighbor rows read as uint2 (4 bf16, 8 B/lane) from xh — halves
// the dominant beyond-L2 x-row traffic. Self rows stay exact fp32.
// Structure identical to the verified round-5 kernel otherwise.
// ---------------------------------------------------------------------------
template <bool BF16>
__global__ __launch_bounds__(256) void gather_linear_kernel(
        const float4* __restrict__ x4,
        const uint2*  __restrict__ xh2,    // bf16 rows, 16 uint2 per row
        const int*    __restrict__ off,
        const int*    __restrict__ cnt,
        const int*    __restrict__ perm,
        const float4* __restrict__ W4,     // [64][32] float4 view of [64][128]
        const float*  __restrict__ b,
        float*        __restrict__ out) {
    __shared__ float4 Wq[32 * 64];         // 32 KB: Wq[c4*64+o] = W[o][4c4..+3]
    __shared__ float4 sq[4][8][16];        // 8 KB: [wave][0-3 aggr | 4-7 self]
    for (int idx = threadIdx.x; idx < 2048; idx += 256) {
        int o = idx & 63, c = idx >> 6;
        Wq[c * 64 + o] = W4[o * 32 + c];
    }
    __syncthreads();

    const int lane = threadIdx.x & 63;
    const int w    = threadIdx.x >> 6;
    const int g    = lane >> 4;            // edge slot 0..3
    const int c4   = lane & 15;            // 4-channel chunk 0..15
    const float bv = b[lane];

    for (int q = blockIdx.x * 4 + w; q < NQUAD; q += NWAVES) {
        const int n0 = __builtin_amdgcn_readfirstlane(q * 4);
        int o0 = off[n0 + 0], o1 = off[n0 + 1], o2 = off[n0 + 2], o3 = off[n0 + 3];
        int d0 = cnt[n0 + 0], d1 = cnt[n0 + 1], d2 = cnt[n0 + 2], d3 = cnt[n0 + 3];
        int m  = max(max(d0, d1), max(d2, d3));
        int itn = (m + 3) >> 2;

        // self rows: one vectorized fp32 load — lane-group g grabs node g's row
        float4 sv = x4[(n0 + g) * 16 + c4];

        float4 A0 = make_float4(0.f, 0.f, 0.f, 0.f);
        float4 A1 = A0, A2 = A0, A3 = A0;
        for (int it = 0, e = g; it < itn; ++it, e += 4) {
            int i0 = (e < d0) ? o0 + e : 0;      // cndmask, no branch
            int i1 = (e < d1) ? o1 + e : 0;
            int i2 = (e < d2) ? o2 + e : 0;
            int i3 = (e < d3) ? o3 + e : 0;
            int s0 = perm[i0], s1 = perm[i1], s2 = perm[i2], s3 = perm[i3];
            float w0 = (e < d0) ? 1.f : 0.f;
            float w1 = (e < d1) ? 1.f : 0.f;
            float w2 = (e < d2) ? 1.f : 0.f;
            float w3 = (e < d3) ? 1.f : 0.f;
            if (BF16) {
                uint2 u0 = xh2[s0 * 16 + c4];
                uint2 u1 = xh2[s1 * 16 + c4];
                uint2 u2 = xh2[s2 * 16 + c4];
                uint2 u3 = xh2[s3 * 16 + c4];
                A0.x = fmaf(w0, __uint_as_float(u0.x << 16),        A0.x);
                A0.y = fmaf(w0, __uint_as_float(u0.x & 0xffff0000u), A0.y);
                A0.z = fmaf(w0, __uint_as_float(u0.y << 16),        A0.z);
                A0.w = fmaf(w0, __uint_as_float(u0.y & 0xffff0000u), A0.w);
                A1.x = fmaf(w1, __uint_as_float(u1.x << 16),        A1.x);
                A1.y = fmaf(w1, __uint_as_float(u1.x & 0xffff0000u), A1.y);
                A1.z = fmaf(w1, __uint_as_float(u1.y << 16),        A1.z);
                A1.w = fmaf(w1, __uint_as_float(u1.y & 0xffff0000u), A1.w);
                A2.x = fmaf(w2, __uint_as_float(u2.x << 16),        A2.x);
                A2.y = fmaf(w2, __uint_as_float(u2.x & 0xffff0000u), A2.y);
                A2.z = fmaf(w2, __uint_as_float(u2.y << 16),        A2.z);
                A2.w = fmaf(w2, __uint_as_float(u2.y & 0xffff0000u), A2.w);
                A3.x = fmaf(w3, __uint_as_float(u3.x << 16),        A3.x);
                A3.y = fmaf(w3, __uint_as_float(u3.x & 0xffff0000u), A3.y);
                A3.z = fmaf(w3, __uint_as_float(u3.y << 16),        A3.z);
                A3.w = fmaf(w3, __uint_as_float(u3.y & 0xffff0000u), A3.w);
            } else {
                float4 v0 = x4[s0 * 16 + c4];
                float4 v1 = x4[s1 * 16 + c4];
                float4 v2 = x4[s2 * 16 + c4];
                float4 v3 = x4[s3 * 16 + c4];
                A0.x = fmaf(w0, v0.x, A0.x); A0.y = fmaf(w0, v0.y, A0.y);
                A0.z = fmaf(w0, v0.z, A0.z); A0.w = fmaf(w0, v0.w, A0.w);
                A1.x = fmaf(w1, v1.x, A1.x); A1.y = fmaf(w1, v1.y, A1.y);
                A1.z = fmaf(w1, v1.z, A1.z); A1.w = fmaf(w1, v1.w, A1.w);
                A2.x = fmaf(w2, v2.x, A2.x); A2.y = fmaf(w2, v2.y, A2.y);
                A2.z = fmaf(w2, v2.z, A2.z); A2.w = fmaf(w2, v2.w, A2.w);
                A3.x = fmaf(w3, v3.x, A3.x); A3.y = fmaf(w3, v3.y, A3.y);
                A3.z = fmaf(w3, v3.z, A3.z); A3.w = fmaf(w3, v3.w, A3.w);
            }
        }

#define RED4(A) \
        A.x += __shfl_xor(A.x, 32, 64); A.x += __shfl_xor(A.x, 16, 64); \
        A.y += __shfl_xor(A.y, 32, 64); A.y += __shfl_xor(A.y, 16, 64); \
        A.z += __shfl_xor(A.z, 32, 64); A.z += __shfl_xor(A.z, 16, 64); \
        A.w += __shfl_xor(A.w, 32, 64); A.w += __shfl_xor(A.w, 16, 64);
        RED4(A0) RED4(A1) RED4(A2) RED4(A3)
#undef RED4

        float inv0 = 1.0f / fmaxf((float)d0, 1.0f);
        float inv1 = 1.0f / fmaxf((float)d1, 1.0f);
        float inv2 = 1.0f / fmaxf((float)d2, 1.0f);
        float inv3 = 1.0f / fmaxf((float)d3, 1.0f);
        if (lane < 16) {
            sq[w][0][c4] = make_float4(A0.x * inv0, A0.y * inv0, A0.z * inv0, A0.w * inv0);
            sq[w][1][c4] = make_float4(A1.x * inv1, A1.y * inv1, A1.z * inv1, A1.w * inv1);
            sq[w][2][c4] = make_float4(A2.x * inv2, A2.y * inv2, A2.z * inv2, A2.w * inv2);
            sq[w][3][c4] = make_float4(A3.x * inv3, A3.y * inv3, A3.z * inv3, A3.w * inv3);
        }
        sq[w][4 + g][c4] = sv;             // self rows
        // no __syncthreads: same-wave LDS write->read, DS pipe is in-order

        float c0 = bv, c1 = bv, c2 = bv, c3 = bv;
#pragma unroll 4
        for (int k = 0; k < 16; ++k) {     // self part: W[:, 0:64]
            float4 wv = Wq[k * 64 + lane];
            float4 v0 = sq[w][4][k], v1 = sq[w][5][k];
            float4 v2 = sq[w][6][k], v3 = sq[w][7][k];
            c0 = fmaf(wv.x, v0.x, fmaf(wv.y, v0.y, fmaf(wv.z, v0.z, fmaf(wv.w, v0.w, c0))));
            c1 = fmaf(wv.x, v1.x, fmaf(wv.y, v1.y, fmaf(wv.z, v1.z, fmaf(wv.w, v1.w, c1))));
            c2 = fmaf(wv.x, v2.x, fmaf(wv.y, v2.y, fmaf(wv.z, v2.z, fmaf(wv.w, v2.w, c2))));
            c3 = fmaf(wv.x, v3.x, fmaf(wv.y, v3.y, fmaf(wv.z, v3.z, fmaf(wv.w, v3.w, c3))));
        }
#pragma unroll 4
        for (int k = 0; k < 16; ++k) {     // aggr part: W[:, 64:128]
            float4 wv = Wq[(16 + k) * 64 + lane];
            float4 v0 = sq[w][0][k], v1 = sq[w][1][k];
            float4 v2 = sq[w][2][k], v3 = sq[w][3][k];
            c0 = fmaf(wv.x, v0.x, fmaf(wv.y, v0.y, fmaf(wv.z, v0.z, fmaf(wv.w, v0.w, c0))));
            c1 = fmaf(wv.x, v1.x, fmaf(wv.y, v1.y, fmaf(wv.z, v1.z, fmaf(wv.w, v1.w, c1))));
            c2 = fmaf(wv.x, v2.x, fmaf(wv.y, v2.y, fmaf(wv.z, v2.z, fmaf(wv.w, v2.w, c2))));
            c3 = fmaf(wv.x, v3.x, fmaf(wv.y, v3.y, fmaf(wv.z, v3.z, fmaf(wv.w, v3.w, c3))));
        }
        out[(n0 + 0) * NC + lane] = c0;
        out[(n0 + 1) * NC + lane] = c1;
        out[(n0 + 2) * NC + lane] = c2;
        out[(n0 + 3) * NC + lane] = c3;
    }
}

// ---------------------------------------------------------------------------
extern "C" void kernel_launch(void* const* d_in, const int* in_sizes, int n_in,
                              void* d_out, int out_size, void* d_ws, size_t ws_size,
                              hipStream_t stream) {
    const float* x   = (const float*)d_in[0];
    const int*   ei  = (const int*)d_in[1];     // [2, NE] flattened
    const float* W   = (const float*)d_in[2];   // [64, 128]
    const float* b   = (const float*)d_in[3];   // [64]
    float*       out = (float*)d_out;

    const int* row = ei;          // source nodes
    const int* col = ei + NE;     // destination nodes

    // ws ints: cnt[NN] | cursor[NN] | gctr[1] | off[NN] | perm[NE] | pad |
    //          xh[NN*NC bf16]  (bf16 region optional, ws-size gated)
    int* cnt    = (int*)d_ws;
    int* cursor = cnt + NN;
    int* gctr   = cursor + NN;
    int* off    = gctr + 1;
    int* perm   = off + NN;
    unsigned short* xh = (unsigned short*)(perm + NE + 1);   // 8B-aligned

    size_t need_bf16 = (size_t)(3 * NN + 2 + NE) * sizeof(int)
                     + (size_t)NN * NC * sizeof(unsigned short);  // ~10.2 MB
    const bool bf = (ws_size >= need_bf16);   // constant across calls

    hipMemsetAsync(cnt, 0, (2 * NN + 1) * sizeof(int), stream);  // cnt+cursor+gctr

    convert_count_kernel<<<bf ? (CONV_BLK + CNT_BLK) : CNT_BLK, 256, 0, stream>>>(
        (const float4*)x, (ushort4*)xh, (const int4*)col, cnt, bf ? 1 : 0);
    offsets_kernel<<<OFF_BLK, 256, 0, stream>>>(cnt, off, gctr);
    fill_kernel<<<CNT_BLK, 256, 0, stream>>>(
        (const int4*)row, (const int4*)col, off, cursor, perm);
    if (bf)
        gather_linear_kernel<true><<<GBLK, 256, 0, stream>>>(
            (const float4*)x, (const uint2*)xh, off, cnt, perm,
            (const float4*)W, b, out);
    else
        gather_linear_kernel<false><<<GBLK, 256, 0, stream>>>(
            (const float4*)x, (const uint2*)xh, off, cnt, perm,
            (const float4*)W, b, out);
}

// Round 7
// 191.479 us; speedup vs baseline: 1.1474x; 1.1474x over previous
//
#include <hip/hip_runtime.h>

#define NN 50000
#define NC 64
#define NE 800000
#define NGRP 3125               // 16-node groups (50000/16 exactly)
#define GBLK 1042               // persistent blocks, <=3 groups each
#define CONV_BLK 3125           // NN*NC/4 float4s / 256 threads
#define CNT_BLK  782            // ceil(NE/4 / 256)
#define OFF_BLK  196            // ceil(NN / 256)
#define TS 288                  // A-tile row stride bytes (128 bf16 + pad, 16B-aligned)

typedef __attribute__((ext_vector_type(8))) short bf16x8;
typedef __attribute__((ext_vector_type(4))) float f32x4;

__device__ __forceinline__ unsigned short f32_to_bf16_rne(float v) {
    unsigned u = __float_as_uint(v);
    u = (u + 0x7fffu + ((u >> 16) & 1u)) >> 16;
    return (unsigned short)u;
}
__device__ __forceinline__ unsigned pack_bf16x2(float lo, float hi) {
    return (unsigned)f32_to_bf16_rne(lo) | ((unsigned)f32_to_bf16_rne(hi) << 16);
}

// ---------------------------------------------------------------------------
// Kernel 1: fused x->bf16 convert (blocks [0,CONV_BLK)) + in-degree count.
// ---------------------------------------------------------------------------
__global__ __launch_bounds__(256) void convert_count_kernel(
        const float4* __restrict__ x4, ushort4* __restrict__ xh4,
        const int4* __restrict__ col4, int* __restrict__ cnt) {
    int b = blockIdx.x;
    if (b < CONV_BLK) {
        int i = b * 256 + threadIdx.x;          // < NN*NC/4 exactly
        float4 v = x4[i];
        ushort4 h;
        h.x = f32_to_bf16_rne(v.x); h.y = f32_to_bf16_rne(v.y);
        h.z = f32_to_bf16_rne(v.z); h.w = f32_to_bf16_rne(v.w);
        xh4[i] = h;
        return;
    }
    int t = (b - CONV_BLK) * 256 + threadIdx.x;
    if (t < NE / 4) {
        int4 c = col4[t];
        atomicAdd(&cnt[c.x], 1); atomicAdd(&cnt[c.y], 1);
        atomicAdd(&cnt[c.z], 1); atomicAdd(&cnt[c.w], 1);
    }
}

// ---------------------------------------------------------------------------
// Kernel 2: offsets — block-local exclusive scan + atomic block base.
// off[] is a valid (non-monotone) partition; lengths come from cnt[].
// ---------------------------------------------------------------------------
__global__ __launch_bounds__(256) void offsets_kernel(
        const int* __restrict__ cnt, int* __restrict__ off,
        int* __restrict__ gctr) {
    __shared__ int s[256];
    __shared__ int base;
    int t = threadIdx.x;
    int i = blockIdx.x * 256 + t;
    int v = (i < NN) ? cnt[i] : 0;
    s[t] = v;
    __syncthreads();
#pragma unroll
    for (int d = 1; d < 256; d <<= 1) {
        int u = (t >= d) ? s[t - d] : 0;
        __syncthreads();
        s[t] += u;
        __syncthreads();
    }
    int excl = s[t] - v;
    if (t == 255) base = atomicAdd(gctr, s[255]);
    __syncthreads();
    if (i < NN) off[i] = base + excl;
}

// ---------------------------------------------------------------------------
// Kernel 3: CSR fill — 4 edges/thread, int atomic cursors
// ---------------------------------------------------------------------------
__global__ __launch_bounds__(256) void fill_kernel(
        const int4* __restrict__ row4, const int4* __restrict__ col4,
        const int* __restrict__ off, int* __restrict__ cursor,
        int* __restrict__ perm) {
    int t = blockIdx.x * blockDim.x + threadIdx.x;
    if (t < NE / 4) {
        int4 r = row4[t];
        int4 c = col4[t];
        perm[off[c.x] + atomicAdd(&cursor[c.x], 1)] = r.x;
        perm[off[c.y] + atomicAdd(&cursor[c.y], 1)] = r.y;
        perm[off[c.z] + atomicAdd(&cursor[c.z], 1)] = r.z;
        perm[off[c.w] + atomicAdd(&cursor[c.w], 1)] = r.w;
    }
}

// ---------------------------------------------------------------------------
// Kernel 4: gather + mean -> bf16 A-tile in LDS -> MFMA linear.
// Block = 4 waves = 16 nodes/group. Gather identical to the verified round-6
// structure (branch-free, 4 slots x 16 chunks, bf16 rows). Linear: each wave
// holds W cols [16w,16w+16) as 4 bf16 B-frags in VGPRs and issues 4
// mfma_f32_16x16x32_bf16 against the shared A-tile (A[m][0:64]=self bf16,
// A[m][64:128]=mean bf16). Bias folded into C-init. LDS = 4.6 KB.
// ---------------------------------------------------------------------------
__global__ __launch_bounds__(256) void gather_mfma_kernel(
        const uint2* __restrict__ xh2,     // bf16 rows, 16 uint2 per row
        const int*   __restrict__ off,
        const int*   __restrict__ cnt,
        const int*   __restrict__ perm,
        const float* __restrict__ W,       // [64][128] fp32 row-major
        const float* __restrict__ b,
        float*       __restrict__ out) {
    __shared__ char tile[16 * TS];         // 16 nodes x 128 bf16 (+pad)

    const int lane = threadIdx.x & 63;
    const int w    = threadIdx.x >> 6;
    const int g    = lane >> 4;            // edge slot / mfma quad
    const int c4   = lane & 15;            // 4-channel chunk / mfma col

    // --- B fragments: B[k][n] = W[o=n][c=k]; lane: n=c4, k=g*8+j (+32*ks) ---
    bf16x8 bfrag[4];
    {
        const float* wr = W + (16 * w + c4) * 128;
#pragma unroll
        for (int ks = 0; ks < 4; ++ks) {
            int k0 = ks * 32 + g * 8;
            float4 f0 = *(const float4*)(wr + k0);
            float4 f1 = *(const float4*)(wr + k0 + 4);
            bf16x8 f;
            f[0] = (short)f32_to_bf16_rne(f0.x);
            f[1] = (short)f32_to_bf16_rne(f0.y);
            f[2] = (short)f32_to_bf16_rne(f0.z);
            f[3] = (short)f32_to_bf16_rne(f0.w);
            f[4] = (short)f32_to_bf16_rne(f1.x);
            f[5] = (short)f32_to_bf16_rne(f1.y);
            f[6] = (short)f32_to_bf16_rne(f1.z);
            f[7] = (short)f32_to_bf16_rne(f1.w);
            bfrag[ks] = f;
        }
    }
    const float bv = b[16 * w + c4];

    for (int gi = blockIdx.x; gi < NGRP; gi += GBLK) {
        const int base = gi * 16;
        const int n0   = base + w * 4;

        int o0 = off[n0 + 0], o1 = off[n0 + 1], o2 = off[n0 + 2], o3 = off[n0 + 3];
        int d0 = cnt[n0 + 0], d1 = cnt[n0 + 1], d2 = cnt[n0 + 2], d3 = cnt[n0 + 3];
        int m  = max(max(d0, d1), max(d2, d3));
        int itn = (m + 3) >> 2;

        // self row (bf16): lane-group g grabs node g's chunk c4
        uint2 sv = xh2[(n0 + g) * 16 + c4];

        float4 A0 = make_float4(0.f, 0.f, 0.f, 0.f);
        float4 A1 = A0, A2 = A0, A3 = A0;
        for (int it = 0, e = g; it < itn; ++it, e += 4) {
            int i0 = (e < d0) ? o0 + e : 0;      // cndmask, no branch
            int i1 = (e < d1) ? o1 + e : 0;
            int i2 = (e < d2) ? o2 + e : 0;
            int i3 = (e < d3) ? o3 + e : 0;
            int s0 = perm[i0], s1 = perm[i1], s2 = perm[i2], s3 = perm[i3];
            float w0 = (e < d0) ? 1.f : 0.f;
            float w1 = (e < d1) ? 1.f : 0.f;
            float w2 = (e < d2) ? 1.f : 0.f;
            float w3 = (e < d3) ? 1.f : 0.f;
            uint2 u0 = xh2[s0 * 16 + c4];
            uint2 u1 = xh2[s1 * 16 + c4];
            uint2 u2 = xh2[s2 * 16 + c4];
            uint2 u3 = xh2[s3 * 16 + c4];
            A0.x = fmaf(w0, __uint_as_float(u0.x << 16),         A0.x);
            A0.y = fmaf(w0, __uint_as_float(u0.x & 0xffff0000u), A0.y);
            A0.z = fmaf(w0, __uint_as_float(u0.y << 16),         A0.z);
            A0.w = fmaf(w0, __uint_as_float(u0.y & 0xffff0000u), A0.w);
            A1.x = fmaf(w1, __uint_as_float(u1.x << 16),         A1.x);
            A1.y = fmaf(w1, __uint_as_float(u1.x & 0xffff0000u), A1.y);
            A1.z = fmaf(w1, __uint_as_float(u1.y << 16),         A1.z);
            A1.w = fmaf(w1, __uint_as_float(u1.y & 0xffff0000u), A1.w);
            A2.x = fmaf(w2, __uint_as_float(u2.x << 16),         A2.x);
            A2.y = fmaf(w2, __uint_as_float(u2.x & 0xffff0000u), A2.y);
            A2.z = fmaf(w2, __uint_as_float(u2.y << 16),         A2.z);
            A2.w = fmaf(w2, __uint_as_float(u2.y & 0xffff0000u), A2.w);
            A3.x = fmaf(w3, __uint_as_float(u3.x << 16),         A3.x);
            A3.y = fmaf(w3, __uint_as_float(u3.x & 0xffff0000u), A3.y);
            A3.z = fmaf(w3, __uint_as_float(u3.y << 16),         A3.z);
            A3.w = fmaf(w3, __uint_as_float(u3.y & 0xffff0000u), A3.w);
        }

#define RED4(A) \
        A.x += __shfl_xor(A.x, 32, 64); A.x += __shfl_xor(A.x, 16, 64); \
        A.y += __shfl_xor(A.y, 32, 64); A.y += __shfl_xor(A.y, 16, 64); \
        A.z += __shfl_xor(A.z, 32, 64); A.z += __shfl_xor(A.z, 16, 64); \
        A.w += __shfl_xor(A.w, 32, 64); A.w += __shfl_xor(A.w, 16, 64);
        RED4(A0) RED4(A1) RED4(A2) RED4(A3)
#undef RED4

        float inv0 = 1.0f / fmaxf((float)d0, 1.0f);
        float inv1 = 1.0f / fmaxf((float)d1, 1.0f);
        float inv2 = 1.0f / fmaxf((float)d2, 1.0f);
        float inv3 = 1.0f / fmaxf((float)d3, 1.0f);

        // A-tile writes: row m = node-in-group, bytes [0,128)=self, [128,256)=mean
        *(uint2*)(tile + (w * 4 + g) * TS + c4 * 8) = sv;   // self
        if (lane < 16) {
            char* r0 = tile + (w * 4 + 0) * TS + 128 + lane * 8;
            char* r1 = tile + (w * 4 + 1) * TS + 128 + lane * 8;
            char* r2 = tile + (w * 4 + 2) * TS + 128 + lane * 8;
            char* r3 = tile + (w * 4 + 3) * TS + 128 + lane * 8;
            *(unsigned*)(r0 + 0) = pack_bf16x2(A0.x * inv0, A0.y * inv0);
            *(unsigned*)(r0 + 4) = pack_bf16x2(A0.z * inv0, A0.w * inv0);
            *(unsigned*)(r1 + 0) = pack_bf16x2(A1.x * inv1, A1.y * inv1);
            *(unsigned*)(r1 + 4) = pack_bf16x2(A1.z * inv1, A1.w * inv1);
            *(unsigned*)(r2 + 0) = pack_bf16x2(A2.x * inv2, A2.y * inv2);
            *(unsigned*)(r2 + 4) = pack_bf16x2(A2.z * inv2, A2.w * inv2);
            *(unsigned*)(r3 + 0) = pack_bf16x2(A3.x * inv3, A3.y * inv3);
            *(unsigned*)(r3 + 4) = pack_bf16x2(A3.z * inv3, A3.w * inv3);
        }
        __syncthreads();

        // MFMA: A[m = c4][k = ks*32 + g*8 + j] from LDS; C init = bias
        f32x4 acc = {bv, bv, bv, bv};
#pragma unroll
        for (int ks = 0; ks < 4; ++ks) {
            bf16x8 af = *(const bf16x8*)(tile + c4 * TS + ks * 64 + g * 16);
            acc = __builtin_amdgcn_mfma_f32_16x16x32_bf16(af, bfrag[ks], acc, 0, 0, 0);
        }
        __syncthreads();       // protect tile from next iteration's writes

        // C layout: col = lane&15 (=c4), row = (lane>>4)*4 + r (=g*4+r)
#pragma unroll
        for (int r = 0; r < 4; ++r)
            out[(base + g * 4 + r) * NC + 16 * w + c4] = acc[r];
    }
}

// ---------------------------------------------------------------------------
extern "C" void kernel_launch(void* const* d_in, const int* in_sizes, int n_in,
                              void* d_out, int out_size, void* d_ws, size_t ws_size,
                              hipStream_t stream) {
    const float* x   = (const float*)d_in[0];
    const int*   ei  = (const int*)d_in[1];     // [2, NE] flattened
    const float* W   = (const float*)d_in[2];   // [64, 128]
    const float* b   = (const float*)d_in[3];   // [64]
    float*       out = (float*)d_out;

    const int* row = ei;          // source nodes
    const int* col = ei + NE;     // destination nodes

    // ws ints: cnt[NN] | cursor[NN] | gctr[1] | off[NN] | perm[NE] | pad |
    //          xh[NN*NC bf16]   (~10.2 MB total; round-6 run verified it fits)
    int* cnt    = (int*)d_ws;
    int* cursor = cnt + NN;
    int* gctr   = cursor + NN;
    int* off    = gctr + 1;
    int* perm   = off + NN;
    unsigned short* xh = (unsigned short*)(perm + NE + 1);   // 8B-aligned

    hipMemsetAsync(cnt, 0, (2 * NN + 1) * sizeof(int), stream);  // cnt+cursor+gctr

    convert_count_kernel<<<CONV_BLK + CNT_BLK, 256, 0, stream>>>(
        (const float4*)x, (ushort4*)xh, (const int4*)col, cnt);
    offsets_kernel<<<OFF_BLK, 256, 0, stream>>>(cnt, off, gctr);
    fill_kernel<<<CNT_BLK, 256, 0, stream>>>(
        (const int4*)row, (const int4*)col, off, cursor, perm);
    gather_mfma_kernel<<<GBLK, 256, 0, stream>>>(
        (const uint2*)xh, off, cnt, perm, W, b, out);
}